// Round 2
// baseline (555.446 us; speedup 1.0000x reference)
//
#include <hip/hip_runtime.h>
#include <hip/hip_bf16.h>

#define NPOS 1600
#define HEADS 8
#define KEY_DIM 16
#define HEAD_DIM 32
#define DIM 256
#define QKV_DIM 512
#define RSEL 320   // ascending 0-based order-stat index (num_keep = 1280)
#define ROWS 4

__device__ __forceinline__ unsigned f2key(float f) {
  unsigned u = __float_as_uint(f);
  return (u & 0x80000000u) ? ~u : (u | 0x80000000u);
}
__device__ __forceinline__ float key2f(unsigned k) {
  unsigned u = (k & 0x80000000u) ? (k & 0x7FFFFFFFu) : ~k;
  return __uint_as_float(u);
}

// ---------------- kernel 1: qkv 1x1 conv (512x256 GEMM over N) ----------------
__global__ __launch_bounds__(256) void qkv_kernel(
    const float* __restrict__ x, const float* __restrict__ wq,
    const float* __restrict__ bq, float* __restrict__ qbuf,
    float* __restrict__ kbuf, float* __restrict__ vbuf) {
  __shared__ float xs[64][65];
  __shared__ float wsh[64][65];
  int t = threadIdx.x;
  int n0 = blockIdx.x * 64;
  int co0 = blockIdx.y * 64;
  int b = blockIdx.z;
  int ct4 = (t >> 4) * 4, nt4 = (t & 15) * 4;
  float acc[4][4] = {};
  for (int cc = 0; cc < 4; ++cc) {
    __syncthreads();
    for (int r = 0; r < 16; ++r) {
      int idx = r * 256 + t;
      int row = idx >> 6, col = idx & 63;
      xs[row][col] = x[((size_t)(b * DIM + cc * 64 + row)) * NPOS + n0 + col];
      wsh[row][col] = wq[(size_t)(co0 + row) * DIM + cc * 64 + col];
    }
    __syncthreads();
    for (int ci = 0; ci < 64; ++ci) {
      float xv[4];
      #pragma unroll
      for (int j = 0; j < 4; ++j) xv[j] = xs[ci][nt4 + j];
      #pragma unroll
      for (int i = 0; i < 4; ++i) {
        float wv = wsh[ct4 + i][ci];
        #pragma unroll
        for (int j = 0; j < 4; ++j) acc[i][j] = fmaf(wv, xv[j], acc[i][j]);
      }
    }
  }
  for (int i = 0; i < 4; ++i) {
    int co = co0 + ct4 + i;
    int hh = co >> 6, rr = co & 63;
    float bias = bq[co];
    for (int j = 0; j < 4; ++j) {
      int n = n0 + nt4 + j;
      float val = acc[i][j] + bias;
      if (rr < KEY_DIM)
        qbuf[((b * HEADS + hh) * KEY_DIM + rr) * NPOS + n] = val;
      else if (rr < 2 * KEY_DIM)
        kbuf[((b * HEADS + hh) * KEY_DIM + (rr - KEY_DIM)) * NPOS + n] = val;
      else
        vbuf[((size_t)(b * DIM + hh * HEAD_DIM + (rr - 2 * KEY_DIM))) * NPOS + n] = val;
    }
  }
}

// ---------------- kernel 2: L2-normalize q,k rows along N ----------------
__global__ __launch_bounds__(256) void norm_kernel(float* __restrict__ qk) {
  __shared__ float red[256];
  int row = blockIdx.x;
  float* p = qk + (size_t)row * NPOS;
  int t = threadIdx.x;
  float ss = 0.0f;
  for (int m = t; m < NPOS; m += 256) { float v = p[m]; ss += v * v; }
  red[t] = ss; __syncthreads();
  for (int off = 128; off > 0; off >>= 1) {
    if (t < off) red[t] += red[t + off];
    __syncthreads();
  }
  float inv = 1.0f / fmaxf(sqrtf(red[0]), 1e-12f);
  for (int m = t; m < NPOS; m += 256) p[m] *= inv;
}

// ---------------- kernel 3: fused attention (QK^T, top-k thr, softmax, PV) ----------------
__global__ __launch_bounds__(256) void attn_kernel(
    const float* __restrict__ qbuf, const float* __restrict__ kbuf,
    const float* __restrict__ vbuf, const float* __restrict__ temp,
    const float* __restrict__ supp, float* __restrict__ ybuf) {
  __shared__ float s[ROWS][NPOS];
  __shared__ unsigned hist[256];
  __shared__ float red[256];
  __shared__ float pvred[256][ROWS + 1];
  __shared__ float qlds[ROWS][KEY_DIM];
  __shared__ int selb, selr;
  int t = threadIdx.x;
  int n0 = blockIdx.x * ROWS;
  int h = blockIdx.y, b = blockIdx.z;
  const float* kbase = kbuf + ((b * HEADS + h) * KEY_DIM) * NPOS;
  if (t < ROWS * KEY_DIM) {
    int i = t >> 4, kk = t & 15;
    qlds[i][kk] = qbuf[((b * HEADS + h) * KEY_DIM + kk) * NPOS + n0 + i];
  }
  __syncthreads();
  float tscale = temp[h];
  float sgm = 1.0f / (1.0f + __expf(-supp[0]));
  // QK^T rows
  for (int m = t; m < NPOS; m += 256) {
    float d0 = 0, d1 = 0, d2 = 0, d3 = 0;
    #pragma unroll
    for (int kk = 0; kk < KEY_DIM; ++kk) {
      float kv = kbase[kk * NPOS + m];
      d0 = fmaf(kv, qlds[0][kk], d0);
      d1 = fmaf(kv, qlds[1][kk], d1);
      d2 = fmaf(kv, qlds[2][kk], d2);
      d3 = fmaf(kv, qlds[3][kk], d3);
    }
    s[0][m] = d0 * tscale; s[1][m] = d1 * tscale;
    s[2][m] = d2 * tscale; s[3][m] = d3 * tscale;
  }
  float inv[ROWS];
  for (int i = 0; i < ROWS; ++i) {
    __syncthreads();
    // exact radix-select: ascending order statistic at index RSEL
    unsigned prefval = 0, maskb = 0;
    int r = RSEL;
    for (int bp = 3; bp >= 0; --bp) {
      hist[t] = 0; __syncthreads();
      for (int m = t; m < NPOS; m += 256) {
        unsigned u = f2key(s[i][m]);
        if (((u ^ prefval) & maskb) == 0)
          atomicAdd(&hist[(u >> (bp * 8)) & 255u], 1u);
      }
      __syncthreads();
      // inclusive Hillis-Steele scan of hist
      for (int off = 1; off < 256; off <<= 1) {
        unsigned v = hist[t];
        if (t >= off) v += hist[t - off];
        __syncthreads();
        hist[t] = v;
        __syncthreads();
      }
      unsigned below = (t > 0) ? hist[t - 1] : 0u;
      if ((int)hist[t] > r && (int)below <= r) { selb = t; selr = r - (int)below; }
      __syncthreads();
      prefval |= ((unsigned)selb) << (bp * 8);
      maskb |= 0xFFu << (bp * 8);
      r = selr;
      __syncthreads();
    }
    float thr = key2f(prefval);
    // masked-weight softmax
    float lmax = -1e30f;
    for (int m = t; m < NPOS; m += 256) {
      float sv = s[i][m];
      float w = (sv >= thr) ? 1.0f : sgm;
      float p = sv * w;
      s[i][m] = p;
      lmax = fmaxf(lmax, p);
    }
    red[t] = lmax; __syncthreads();
    for (int off = 128; off > 0; off >>= 1) {
      if (t < off) red[t] = fmaxf(red[t], red[t + off]);
      __syncthreads();
    }
    float rmax = red[0]; __syncthreads();
    float lsum = 0.0f;
    for (int m = t; m < NPOS; m += 256) {
      float e = __expf(s[i][m] - rmax);
      s[i][m] = e;
      lsum += e;
    }
    red[t] = lsum; __syncthreads();
    for (int off = 128; off > 0; off >>= 1) {
      if (t < off) red[t] += red[t + off];
      __syncthreads();
    }
    inv[i] = 1.0f / red[0];
    __syncthreads();
  }
  // PV: out[d, n0+i] = sum_m V[d,m] * p_i[m] * inv[i]
  int d = t >> 3, sub = t & 7;
  const float* vrow = vbuf + ((size_t)(b * DIM + h * HEAD_DIM + d)) * NPOS;
  float acc[ROWS] = {};
  for (int m = sub; m < NPOS; m += 8) {
    float vv = vrow[m];
    #pragma unroll
    for (int i = 0; i < ROWS; ++i) acc[i] = fmaf(vv, s[i][m], acc[i]);
  }
  #pragma unroll
  for (int i = 0; i < ROWS; ++i) pvred[t][i] = acc[i];
  __syncthreads();
  if (sub == 0) {
    #pragma unroll
    for (int i = 0; i < ROWS; ++i) {
      float a = pvred[t][i];
      for (int ss2 = 1; ss2 < 8; ++ss2) a += pvred[t + ss2][i];
      ybuf[((size_t)(b * DIM + h * HEAD_DIM + d)) * NPOS + n0 + i] = a * inv[i];
    }
  }
}

// ---------------- kernel 4: depthwise 3x3 pe conv on v, add in place ----------------
__global__ __launch_bounds__(256) void pe_kernel(
    const float* __restrict__ vbuf, const float* __restrict__ wpe,
    const float* __restrict__ bpe, float* __restrict__ ybuf) {
  int c = blockIdx.x, b = blockIdx.y;
  const float* vp = vbuf + (size_t)(b * DIM + c) * NPOS;
  float* yp = ybuf + (size_t)(b * DIM + c) * NPOS;
  const float* w9 = wpe + c * 9;
  float w[9];
  #pragma unroll
  for (int i = 0; i < 9; ++i) w[i] = w9[i];
  float bias = bpe[c];
  for (int p = threadIdx.x; p < NPOS; p += 256) {
    int py = p / 40, px = p - py * 40;
    float acc = bias;
    #pragma unroll
    for (int dy = -1; dy <= 1; ++dy)
      #pragma unroll
      for (int dx = -1; dx <= 1; ++dx) {
        int iy = py + dy, ix = px + dx;
        if (iy >= 0 && iy < 40 && ix >= 0 && ix < 40)
          acc = fmaf(vp[iy * 40 + ix], w[(dy + 1) * 3 + (dx + 1)], acc);
      }
    yp[p] += acc;
  }
}

// ---------------- kernel 5: proj 1x1 conv -> fp32 out ----------------
__global__ __launch_bounds__(256) void proj_kernel(
    const float* __restrict__ y, const float* __restrict__ wp,
    const float* __restrict__ bp, float* __restrict__ out) {
  __shared__ float xs[64][65];
  __shared__ float wsh[64][65];
  int t = threadIdx.x;
  int n0 = blockIdx.x * 64;
  int co0 = blockIdx.y * 64;
  int b = blockIdx.z;
  int ct4 = (t >> 4) * 4, nt4 = (t & 15) * 4;
  float acc[4][4] = {};
  for (int cc = 0; cc < 4; ++cc) {
    __syncthreads();
    for (int r = 0; r < 16; ++r) {
      int idx = r * 256 + t;
      int row = idx >> 6, col = idx & 63;
      xs[row][col] = y[((size_t)(b * DIM + cc * 64 + row)) * NPOS + n0 + col];
      wsh[row][col] = wp[(size_t)(co0 + row) * DIM + cc * 64 + col];
    }
    __syncthreads();
    for (int ci = 0; ci < 64; ++ci) {
      float xv[4];
      #pragma unroll
      for (int j = 0; j < 4; ++j) xv[j] = xs[ci][nt4 + j];
      #pragma unroll
      for (int i = 0; i < 4; ++i) {
        float wv = wsh[ct4 + i][ci];
        #pragma unroll
        for (int j = 0; j < 4; ++j) acc[i][j] = fmaf(wv, xv[j], acc[i][j]);
      }
    }
  }
  for (int i = 0; i < 4; ++i) {
    int co = co0 + ct4 + i;
    float bias = bp[co];
    for (int j = 0; j < 4; ++j) {
      int n = n0 + nt4 + j;
      out[(size_t)(b * DIM + co) * NPOS + n] = acc[i][j] + bias;
    }
  }
}

extern "C" void kernel_launch(void* const* d_in, const int* in_sizes, int n_in,
                              void* d_out, int out_size, void* d_ws, size_t ws_size,
                              hipStream_t stream) {
  (void)in_sizes; (void)n_in; (void)out_size; (void)ws_size;
  const float* x = (const float*)d_in[0];
  const float* w_qkv = (const float*)d_in[1];
  const float* b_qkv = (const float*)d_in[2];
  const float* w_proj = (const float*)d_in[3];
  const float* b_proj = (const float*)d_in[4];
  const float* w_pe = (const float*)d_in[5];
  const float* b_pe = (const float*)d_in[6];
  const float* temperature = (const float*)d_in[7];
  const float* supp = (const float*)d_in[8];

  float* wsf = (float*)d_ws;
  float* qbuf = wsf;                                   // 409600 f
  float* kbuf = qbuf + 2 * HEADS * KEY_DIM * NPOS;     // 409600 f
  float* vbuf = kbuf + 2 * HEADS * KEY_DIM * NPOS;     // 819200 f
  float* ybuf = vbuf + 2 * DIM * NPOS;                 // 819200 f
  float* out = (float*)d_out;

  qkv_kernel<<<dim3(25, 8, 2), 256, 0, stream>>>(x, w_qkv, b_qkv, qbuf, kbuf, vbuf);
  norm_kernel<<<512, 256, 0, stream>>>(qbuf);  // q rows 0..255, k rows 256..511 (contiguous)
  attn_kernel<<<dim3(NPOS / ROWS, HEADS, 2), 256, 0, stream>>>(qbuf, kbuf, vbuf, temperature, supp, ybuf);
  pe_kernel<<<dim3(DIM, 2), 256, 0, stream>>>(vbuf, w_pe, b_pe, ybuf);
  proj_kernel<<<dim3(25, 4, 2), 256, 0, stream>>>(ybuf, w_proj, b_proj, out);
}

// Round 3
// 279.590 us; speedup vs baseline: 1.9866x; 1.9866x over previous
//
#include <hip/hip_runtime.h>
#include <hip/hip_bf16.h>

#define NPOS 1600
#define HEADS 8
#define KEY_DIM 16
#define HEAD_DIM 32
#define DIM 256
#define QKV_DIM 512
#define RSEL 320   // ascending 0-based order-stat index (num_keep = 1280)
#define ROWS 4
#define NBINS 256

// ---------------- kernel 1: qkv 1x1 conv (512x256 GEMM over N) ----------------
__global__ __launch_bounds__(256) void qkv_kernel(
    const float* __restrict__ x, const float* __restrict__ wq,
    const float* __restrict__ bq, float* __restrict__ qbuf,
    float* __restrict__ kbuf, float* __restrict__ vbuf) {
  __shared__ float xs[64][65];
  __shared__ float wsh[64][65];
  int t = threadIdx.x;
  int n0 = blockIdx.x * 64;
  int co0 = blockIdx.y * 64;
  int b = blockIdx.z;
  int ct4 = (t >> 4) * 4, nt4 = (t & 15) * 4;
  float acc[4][4] = {};
  for (int cc = 0; cc < 4; ++cc) {
    __syncthreads();
    for (int r = 0; r < 16; ++r) {
      int idx = r * 256 + t;
      int row = idx >> 6, col = idx & 63;
      xs[row][col] = x[((size_t)(b * DIM + cc * 64 + row)) * NPOS + n0 + col];
      wsh[row][col] = wq[(size_t)(co0 + row) * DIM + cc * 64 + col];
    }
    __syncthreads();
    for (int ci = 0; ci < 64; ++ci) {
      float xv[4];
      #pragma unroll
      for (int j = 0; j < 4; ++j) xv[j] = xs[ci][nt4 + j];
      #pragma unroll
      for (int i = 0; i < 4; ++i) {
        float wv = wsh[ct4 + i][ci];
        #pragma unroll
        for (int j = 0; j < 4; ++j) acc[i][j] = fmaf(wv, xv[j], acc[i][j]);
      }
    }
  }
  for (int i = 0; i < 4; ++i) {
    int co = co0 + ct4 + i;
    int hh = co >> 6, rr = co & 63;
    float bias = bq[co];
    for (int j = 0; j < 4; ++j) {
      int n = n0 + nt4 + j;
      float val = acc[i][j] + bias;
      if (rr < KEY_DIM)
        qbuf[((b * HEADS + hh) * KEY_DIM + rr) * NPOS + n] = val;
      else if (rr < 2 * KEY_DIM)
        kbuf[((b * HEADS + hh) * KEY_DIM + (rr - KEY_DIM)) * NPOS + n] = val;
      else
        vbuf[((size_t)(b * DIM + hh * HEAD_DIM + (rr - 2 * KEY_DIM))) * NPOS + n] = val;
    }
  }
}

// ---------------- kernel 2: L2-normalize q,k rows along N ----------------
__global__ __launch_bounds__(256) void norm_kernel(float* __restrict__ qk) {
  __shared__ float red[256];
  int row = blockIdx.x;
  float* p = qk + (size_t)row * NPOS;
  int t = threadIdx.x;
  float ss = 0.0f;
  for (int m = t; m < NPOS; m += 256) { float v = p[m]; ss += v * v; }
  red[t] = ss; __syncthreads();
  for (int off = 128; off > 0; off >>= 1) {
    if (t < off) red[t] += red[t + off];
    __syncthreads();
  }
  float inv = 1.0f / fmaxf(sqrtf(red[0]), 1e-12f);
  for (int m = t; m < NPOS; m += 256) p[m] *= inv;
}

// ---------------- kernel 3: fused attention ----------------
// block = 256 threads = 4 waves; wave w owns row n0+w for select+softmax.
__global__ __launch_bounds__(256) void attn_kernel(
    const float* __restrict__ qbuf, const float* __restrict__ kbuf,
    const float* __restrict__ vbuf, const float* __restrict__ temp,
    const float* __restrict__ supp, float* __restrict__ ybuf) {
  __shared__ float s[ROWS][NPOS];
  __shared__ unsigned hist[ROWS][NBINS];
  __shared__ float qlds[ROWS][KEY_DIM];
  __shared__ float invs[ROWS];
  int t = threadIdx.x;
  int lane = t & 63, w = t >> 6;
  int n0 = blockIdx.x * ROWS;
  int h = blockIdx.y, b = blockIdx.z;
  const float* kbase = kbuf + ((b * HEADS + h) * KEY_DIM) * NPOS;

  if (t < ROWS * KEY_DIM) {
    int i = t >> 4, kk = t & 15;
    qlds[i][kk] = qbuf[((b * HEADS + h) * KEY_DIM + kk) * NPOS + n0 + i];
  }
  // zero all 4 histograms (1024 bins) before the barrier
  unsigned* hf = (unsigned*)hist;
  hf[t] = 0; hf[t + 256] = 0; hf[t + 512] = 0; hf[t + 768] = 0;
  __syncthreads();

  float tscale = temp[h];
  float sgm = 1.0f / (1.0f + __expf(-supp[0]));

  // ---- QK^T: float4 over m, all 256 threads ----
  const float4* k4 = (const float4*)kbase;  // row stride 400 float4
  for (int c = t; c < NPOS / 4; c += 256) {
    float a[ROWS][4] = {};
    #pragma unroll
    for (int kk = 0; kk < KEY_DIM; ++kk) {
      float4 kv = k4[kk * (NPOS / 4) + c];
      float kvv[4] = {kv.x, kv.y, kv.z, kv.w};
      #pragma unroll
      for (int i = 0; i < ROWS; ++i) {
        float qv = qlds[i][kk];
        #pragma unroll
        for (int j = 0; j < 4; ++j) a[i][j] = fmaf(kvv[j], qv, a[i][j]);
      }
    }
    #pragma unroll
    for (int i = 0; i < ROWS; ++i) {
      float4 o = {a[i][0] * tscale, a[i][1] * tscale, a[i][2] * tscale, a[i][3] * tscale};
      ((float4*)s[i])[c] = o;
    }
  }
  __syncthreads();

  // ---- per-wave: min/max + linear histogram ----
  float sv[25];
  float mn = 3.4e38f, mx = -3.4e38f;
  #pragma unroll
  for (int k = 0; k < 25; ++k) {
    float v = s[w][lane + 64 * k];
    sv[k] = v;
    mn = fminf(mn, v); mx = fmaxf(mx, v);
  }
  #pragma unroll
  for (int o = 32; o; o >>= 1) {
    mn = fminf(mn, __shfl_xor(mn, o, 64));
    mx = fmaxf(mx, __shfl_xor(mx, o, 64));
  }
  float range = fmaxf(mx - mn, 1e-30f) * 1.000001f;
  float invw = (float)NBINS / range;
  #pragma unroll
  for (int k = 0; k < 25; ++k) {
    int idx = (int)((sv[k] - mn) * invw);
    idx = idx < 0 ? 0 : (idx > NBINS - 1 ? NBINS - 1 : idx);
    atomicAdd(&hist[w][idx], 1u);
  }
  __syncthreads();

  // ---- per-wave: scan 256 bins (4/lane), find rank-RSEL bin ----
  int h0 = (int)hist[w][4 * lane], h1 = (int)hist[w][4 * lane + 1];
  int h2 = (int)hist[w][4 * lane + 2], h3 = (int)hist[w][4 * lane + 3];
  int lsum = h0 + h1 + h2 + h3;
  int incl = lsum;
  #pragma unroll
  for (int o = 1; o < 64; o <<= 1) {
    int xx = __shfl_up(incl, o, 64);
    if (lane >= o) incl += xx;
  }
  int c = incl - lsum;  // exclusive prefix
  int cand = 1 << 30;
  if (c <= RSEL && c + h0 > RSEL) cand = 4 * lane;
  c += h0; if (c <= RSEL && c + h1 > RSEL) cand = 4 * lane + 1;
  c += h1; if (c <= RSEL && c + h2 > RSEL) cand = 4 * lane + 2;
  c += h2; if (c <= RSEL && c + h3 > RSEL) cand = 4 * lane + 3;
  #pragma unroll
  for (int o = 32; o; o >>= 1) cand = min(cand, __shfl_xor(cand, o, 64));
  float thr = mn + (float)cand * (range / (float)NBINS);

  // ---- per-wave softmax ----
  float lmax = -3.4e38f;
  #pragma unroll
  for (int k = 0; k < 25; ++k) {
    float p = sv[k] * (sv[k] >= thr ? 1.0f : sgm);
    sv[k] = p;
    lmax = fmaxf(lmax, p);
  }
  #pragma unroll
  for (int o = 32; o; o >>= 1) lmax = fmaxf(lmax, __shfl_xor(lmax, o, 64));
  float lsumf = 0.0f;
  #pragma unroll
  for (int k = 0; k < 25; ++k) {
    float e = __expf(sv[k] - lmax);
    s[w][lane + 64 * k] = e;
    lsumf += e;
  }
  #pragma unroll
  for (int o = 32; o; o >>= 1) lsumf += __shfl_xor(lsumf, o, 64);
  if (lane == 0) invs[w] = 1.0f / lsumf;
  __syncthreads();

  // ---- PV: thread t handles d=(t>>4) and d+16, m = (t&15)+16k, float2 ----
  int d = t >> 4;        // 0..15
  int sub = t & 15;
  const float2* v2a = (const float2*)(vbuf + ((size_t)(b * DIM + h * HEAD_DIM + d)) * NPOS);
  const float2* v2b = (const float2*)(vbuf + ((size_t)(b * DIM + h * HEAD_DIM + d + 16)) * NPOS);
  float2 a0[ROWS] = {}, a1[ROWS] = {};
  for (int k = 0; k < 50; ++k) {
    int m2 = sub + 16 * k;
    float2 v0 = v2a[m2], v1 = v2b[m2];
    #pragma unroll
    for (int i = 0; i < ROWS; ++i) {
      float2 p2 = ((const float2*)s[i])[m2];
      a0[i].x = fmaf(v0.x, p2.x, a0[i].x); a0[i].y = fmaf(v0.y, p2.y, a0[i].y);
      a1[i].x = fmaf(v1.x, p2.x, a1[i].x); a1[i].y = fmaf(v1.y, p2.y, a1[i].y);
    }
  }
  float r0[ROWS], r1[ROWS];
  #pragma unroll
  for (int i = 0; i < ROWS; ++i) { r0[i] = a0[i].x + a0[i].y; r1[i] = a1[i].x + a1[i].y; }
  #pragma unroll
  for (int o = 1; o < 16; o <<= 1) {
    #pragma unroll
    for (int i = 0; i < ROWS; ++i) {
      r0[i] += __shfl_xor(r0[i], o, 64);
      r1[i] += __shfl_xor(r1[i], o, 64);
    }
  }
  if (sub == 0) {
    size_t base0 = ((size_t)(b * DIM + h * HEAD_DIM + d)) * NPOS + n0;
    size_t base1 = base0 + (size_t)16 * NPOS;
    #pragma unroll
    for (int i = 0; i < ROWS; ++i) {
      float iv = invs[i];
      ybuf[base0 + i] = r0[i] * iv;
      ybuf[base1 + i] = r1[i] * iv;
    }
  }
}

// ---------------- kernel 4: depthwise 3x3 pe conv on v, add in place ----------------
__global__ __launch_bounds__(256) void pe_kernel(
    const float* __restrict__ vbuf, const float* __restrict__ wpe,
    const float* __restrict__ bpe, float* __restrict__ ybuf) {
  int c = blockIdx.x, b = blockIdx.y;
  const float* vp = vbuf + (size_t)(b * DIM + c) * NPOS;
  float* yp = ybuf + (size_t)(b * DIM + c) * NPOS;
  const float* w9 = wpe + c * 9;
  float w[9];
  #pragma unroll
  for (int i = 0; i < 9; ++i) w[i] = w9[i];
  float bias = bpe[c];
  for (int p = threadIdx.x; p < NPOS; p += 256) {
    int py = p / 40, px = p - py * 40;
    float acc = bias;
    #pragma unroll
    for (int dy = -1; dy <= 1; ++dy)
      #pragma unroll
      for (int dx = -1; dx <= 1; ++dx) {
        int iy = py + dy, ix = px + dx;
        if (iy >= 0 && iy < 40 && ix >= 0 && ix < 40)
          acc = fmaf(vp[iy * 40 + ix], w[(dy + 1) * 3 + (dx + 1)], acc);
      }
    yp[p] += acc;
  }
}

// ---------------- kernel 5: proj 1x1 conv -> fp32 out ----------------
__global__ __launch_bounds__(256) void proj_kernel(
    const float* __restrict__ y, const float* __restrict__ wp,
    const float* __restrict__ bp, float* __restrict__ out) {
  __shared__ float xs[64][65];
  __shared__ float wsh[64][65];
  int t = threadIdx.x;
  int n0 = blockIdx.x * 64;
  int co0 = blockIdx.y * 64;
  int b = blockIdx.z;
  int ct4 = (t >> 4) * 4, nt4 = (t & 15) * 4;
  float acc[4][4] = {};
  for (int cc = 0; cc < 4; ++cc) {
    __syncthreads();
    for (int r = 0; r < 16; ++r) {
      int idx = r * 256 + t;
      int row = idx >> 6, col = idx & 63;
      xs[row][col] = y[((size_t)(b * DIM + cc * 64 + row)) * NPOS + n0 + col];
      wsh[row][col] = wp[(size_t)(co0 + row) * DIM + cc * 64 + col];
    }
    __syncthreads();
    for (int ci = 0; ci < 64; ++ci) {
      float xv[4];
      #pragma unroll
      for (int j = 0; j < 4; ++j) xv[j] = xs[ci][nt4 + j];
      #pragma unroll
      for (int i = 0; i < 4; ++i) {
        float wv = wsh[ct4 + i][ci];
        #pragma unroll
        for (int j = 0; j < 4; ++j) acc[i][j] = fmaf(wv, xv[j], acc[i][j]);
      }
    }
  }
  for (int i = 0; i < 4; ++i) {
    int co = co0 + ct4 + i;
    float bias = bp[co];
    for (int j = 0; j < 4; ++j) {
      int n = n0 + nt4 + j;
      out[(size_t)(b * DIM + co) * NPOS + n] = acc[i][j] + bias;
    }
  }
}

extern "C" void kernel_launch(void* const* d_in, const int* in_sizes, int n_in,
                              void* d_out, int out_size, void* d_ws, size_t ws_size,
                              hipStream_t stream) {
  (void)in_sizes; (void)n_in; (void)out_size; (void)ws_size;
  const float* x = (const float*)d_in[0];
  const float* w_qkv = (const float*)d_in[1];
  const float* b_qkv = (const float*)d_in[2];
  const float* w_proj = (const float*)d_in[3];
  const float* b_proj = (const float*)d_in[4];
  const float* w_pe = (const float*)d_in[5];
  const float* b_pe = (const float*)d_in[6];
  const float* temperature = (const float*)d_in[7];
  const float* supp = (const float*)d_in[8];

  float* wsf = (float*)d_ws;
  float* qbuf = wsf;                                   // 409600 f
  float* kbuf = qbuf + 2 * HEADS * KEY_DIM * NPOS;     // 409600 f
  float* vbuf = kbuf + 2 * HEADS * KEY_DIM * NPOS;     // 819200 f
  float* ybuf = vbuf + 2 * DIM * NPOS;                 // 819200 f
  float* out = (float*)d_out;

  qkv_kernel<<<dim3(25, 8, 2), 256, 0, stream>>>(x, w_qkv, b_qkv, qbuf, kbuf, vbuf);
  norm_kernel<<<512, 256, 0, stream>>>(qbuf);  // q rows 0..255, k rows 256..511 (contiguous)
  attn_kernel<<<dim3(NPOS / ROWS, HEADS, 2), 256, 0, stream>>>(qbuf, kbuf, vbuf, temperature, supp, ybuf);
  pe_kernel<<<dim3(DIM, 2), 256, 0, stream>>>(vbuf, w_pe, b_pe, ybuf);
  proj_kernel<<<dim3(25, 4, 2), 256, 0, stream>>>(ybuf, w_proj, b_proj, out);
}

// Round 4
// 201.688 us; speedup vs baseline: 2.7540x; 1.3863x over previous
//
#include <hip/hip_runtime.h>
#include <hip/hip_bf16.h>

#define NPOS 1600
#define HEADS 8
#define KEY_DIM 16
#define HEAD_DIM 32
#define DIM 256
#define QKV_DIM 512
#define RSEL 320   // ascending 0-based order-stat index (num_keep = 1280)
#define QBLK 16
#define NBINS 256

typedef __attribute__((ext_vector_type(8))) short short8;
typedef __attribute__((ext_vector_type(4))) float f32x4;

__device__ __forceinline__ unsigned short f2b(float f) {
  unsigned u = __float_as_uint(f);
  unsigned r = u + 0x7FFFu + ((u >> 16) & 1u);
  return (unsigned short)(r >> 16);
}
__device__ __forceinline__ float b2f(unsigned short h) {
  return __uint_as_float(((unsigned)h) << 16);
}

// ---------------- kernel 1: qkv 1x1 conv (512x256 GEMM over N) ----------------
__global__ __launch_bounds__(256) void qkv_kernel(
    const float* __restrict__ x, const float* __restrict__ wq,
    const float* __restrict__ bq, float* __restrict__ qbuf,
    float* __restrict__ kbuf, float* __restrict__ vbuf) {
  __shared__ float xs[64][65];
  __shared__ float wsh[64][65];
  int t = threadIdx.x;
  int n0 = blockIdx.x * 64;
  int co0 = blockIdx.y * 64;
  int b = blockIdx.z;
  int ct4 = (t >> 4) * 4, nt4 = (t & 15) * 4;
  float acc[4][4] = {};
  for (int cc = 0; cc < 4; ++cc) {
    __syncthreads();
    for (int r = 0; r < 16; ++r) {
      int idx = r * 256 + t;
      int row = idx >> 6, col = idx & 63;
      xs[row][col] = x[((size_t)(b * DIM + cc * 64 + row)) * NPOS + n0 + col];
      wsh[row][col] = wq[(size_t)(co0 + row) * DIM + cc * 64 + col];
    }
    __syncthreads();
    for (int ci = 0; ci < 64; ++ci) {
      float xv[4];
      #pragma unroll
      for (int j = 0; j < 4; ++j) xv[j] = xs[ci][nt4 + j];
      #pragma unroll
      for (int i = 0; i < 4; ++i) {
        float wv = wsh[ct4 + i][ci];
        #pragma unroll
        for (int j = 0; j < 4; ++j) acc[i][j] = fmaf(wv, xv[j], acc[i][j]);
      }
    }
  }
  for (int i = 0; i < 4; ++i) {
    int co = co0 + ct4 + i;
    int hh = co >> 6, rr = co & 63;
    float bias = bq[co];
    for (int j = 0; j < 4; ++j) {
      int n = n0 + nt4 + j;
      float val = acc[i][j] + bias;
      if (rr < KEY_DIM)
        qbuf[((b * HEADS + hh) * KEY_DIM + rr) * NPOS + n] = val;
      else if (rr < 2 * KEY_DIM)
        kbuf[((b * HEADS + hh) * KEY_DIM + (rr - KEY_DIM)) * NPOS + n] = val;
      else
        vbuf[((size_t)(b * DIM + hh * HEAD_DIM + (rr - 2 * KEY_DIM))) * NPOS + n] = val;
    }
  }
}

// ---------------- kernel 2: L2-normalize q,k rows + emit bf16 transposed ----------------
// qk = [qbuf(256 rows) | kbuf(256 rows)] contiguous; row r: bh=(r&255)>>4, kk=r&15.
// Output layout: [bh][n][kk] bf16 (row = 16 bf16 = 32B), for MFMA fragment loads.
__global__ __launch_bounds__(256) void norm_kernel(
    const float* __restrict__ qk, unsigned short* __restrict__ qT16,
    unsigned short* __restrict__ kT16) {
  __shared__ float red[256];
  int row = blockIdx.x;
  const float* p = qk + (size_t)row * NPOS;
  int t = threadIdx.x;
  float ss = 0.0f;
  for (int m = t; m < NPOS; m += 256) { float v = p[m]; ss += v * v; }
  red[t] = ss; __syncthreads();
  for (int off = 128; off > 0; off >>= 1) {
    if (t < off) red[t] += red[t + off];
    __syncthreads();
  }
  float inv = 1.0f / fmaxf(sqrtf(red[0]), 1e-12f);
  unsigned short* dst = (row < 256) ? qT16 : kT16;
  int rr = row & 255;
  int bh = rr >> 4, kk = rr & 15;
  for (int m = t; m < NPOS; m += 256)
    dst[((size_t)bh * NPOS + m) * KEY_DIM + kk] = f2b(p[m] * inv);
}

// ---------------- kernel 3: fused attention, MFMA ----------------
// 512 threads = 8 waves. QBLK=16 q-rows per block, one (b,h).
// S/P tile in LDS bf16, XOR-swizzled: byte ^= (row&7)<<4 (rows are 3200B, 128-aligned).
__global__ __launch_bounds__(512) void attn_kernel(
    const unsigned short* __restrict__ qT16, const unsigned short* __restrict__ kT16,
    const float* __restrict__ vbuf, const float* __restrict__ temp,
    const float* __restrict__ supp, float* __restrict__ ybuf) {
  __shared__ __align__(128) unsigned short s16[QBLK * NPOS];  // 51200 B
  __shared__ unsigned hist[8][NBINS];
  __shared__ float red[8][256];
  __shared__ float invs[QBLK];
  int t = threadIdx.x, lane = t & 63, w = t >> 6;
  int l15 = lane & 15, lg = lane >> 4;
  int n0 = blockIdx.x * QBLK;
  int h = blockIdx.y, b = blockIdx.z;
  int bh = b * HEADS + h;
  float tscale = temp[h];
  float sgm = 1.0f / (1.0f + __expf(-supp[0]));

  // A-frag: Q^T tile (16 q-rows x K=32, kk>=16 zero-padded via lanes>=32)
  short8 qa = {0, 0, 0, 0, 0, 0, 0, 0};
  if (lane < 32)
    qa = *(const short8*)(qT16 + ((size_t)bh * NPOS + n0 + l15) * KEY_DIM + lg * 8);

  // ---- QK^T: 100 m-tiles of 16, split across 8 waves ----
  for (int mt = w; mt < NPOS / 16; mt += 8) {
    int m0 = mt * 16;
    short8 kb = {0, 0, 0, 0, 0, 0, 0, 0};
    if (lane < 32)
      kb = *(const short8*)(kT16 + ((size_t)bh * NPOS + m0 + l15) * KEY_DIM + lg * 8);
    f32x4 acc = {0.f, 0.f, 0.f, 0.f};
    acc = __builtin_amdgcn_mfma_f32_16x16x32_bf16(qa, kb, acc, 0, 0, 0);
    #pragma unroll
    for (int r = 0; r < 4; ++r) {
      int row = lg * 4 + r;  // q-row within tile
      int byteoff = (row * 3200 + (m0 + l15) * 2) ^ ((row & 7) << 4);
      s16[byteoff >> 1] = f2b(acc[r] * tscale);
    }
  }
  __syncthreads();

  // ---- per-wave select + softmax: wave w owns rows 2w, 2w+1 ----
  for (int rl = 0; rl < 2; ++rl) {
    int rr = w * 2 + rl;
    int rbase = rr * 3200, xr = (rr & 7) << 4;
    float sv[25];
    float mn = 3.4e38f, mx = -3.4e38f;
    #pragma unroll
    for (int k = 0; k < 25; ++k) {
      int byteoff = rbase + (((lane + 64 * k) * 2) ^ xr);
      float v = b2f(s16[byteoff >> 1]);
      sv[k] = v; mn = fminf(mn, v); mx = fmaxf(mx, v);
    }
    #pragma unroll
    for (int k4 = 0; k4 < 4; ++k4) hist[w][lane * 4 + k4] = 0;
    #pragma unroll
    for (int o = 32; o; o >>= 1) {
      mn = fminf(mn, __shfl_xor(mn, o, 64));
      mx = fmaxf(mx, __shfl_xor(mx, o, 64));
    }
    float range = fmaxf(mx - mn, 1e-30f) * 1.000001f;
    float invw = (float)NBINS / range;
    #pragma unroll
    for (int k = 0; k < 25; ++k) {
      int idx = (int)((sv[k] - mn) * invw);
      idx = idx < 0 ? 0 : (idx > NBINS - 1 ? NBINS - 1 : idx);
      atomicAdd(&hist[w][idx], 1u);
    }
    int h0 = (int)hist[w][4 * lane], h1 = (int)hist[w][4 * lane + 1];
    int h2 = (int)hist[w][4 * lane + 2], h3 = (int)hist[w][4 * lane + 3];
    int lsum = h0 + h1 + h2 + h3;
    int incl = lsum;
    #pragma unroll
    for (int o = 1; o < 64; o <<= 1) {
      int xx = __shfl_up(incl, o, 64);
      if (lane >= o) incl += xx;
    }
    int c = incl - lsum;
    int cand = 1 << 30;
    if (c <= RSEL && c + h0 > RSEL) cand = 4 * lane;
    c += h0; if (c <= RSEL && c + h1 > RSEL) cand = 4 * lane + 1;
    c += h1; if (c <= RSEL && c + h2 > RSEL) cand = 4 * lane + 2;
    c += h2; if (c <= RSEL && c + h3 > RSEL) cand = 4 * lane + 3;
    #pragma unroll
    for (int o = 32; o; o >>= 1) cand = min(cand, __shfl_xor(cand, o, 64));
    float thr = mn + (float)cand * (range / (float)NBINS);

    float lmax = -3.4e38f;
    #pragma unroll
    for (int k = 0; k < 25; ++k) {
      float p = sv[k] * (sv[k] >= thr ? 1.0f : sgm);
      sv[k] = p;
      lmax = fmaxf(lmax, p);
    }
    #pragma unroll
    for (int o = 32; o; o >>= 1) lmax = fmaxf(lmax, __shfl_xor(lmax, o, 64));
    float lsumf = 0.0f;
    #pragma unroll
    for (int k = 0; k < 25; ++k) {
      float e = __expf(sv[k] - lmax);
      lsumf += e;
      int byteoff = rbase + (((lane + 64 * k) * 2) ^ xr);
      s16[byteoff >> 1] = f2b(e);  // P (unnormalized) back to same slots
    }
    #pragma unroll
    for (int o = 32; o; o >>= 1) lsumf += __shfl_xor(lsumf, o, 64);
    if (lane == 0) invs[rr] = 1.0f / lsumf;
  }
  __syncthreads();

  // ---- PV: out[32 d x 16 n]; wave w -> d-tile (w&1), m-chunks (w>>1)+4k ----
  int tile = w & 1, d0 = tile * 16;
  const float* vrow = vbuf + ((size_t)(b * DIM + h * HEAD_DIM + d0 + l15)) * NPOS;
  f32x4 acc = {0.f, 0.f, 0.f, 0.f};
  for (int c = (w >> 1); c < NPOS / 32; c += 4) {
    int m0 = c * 32 + lg * 8;
    float4 v0 = *(const float4*)(vrow + m0);
    float4 v1 = *(const float4*)(vrow + m0 + 4);
    short8 va;
    va[0] = (short)f2b(v0.x); va[1] = (short)f2b(v0.y);
    va[2] = (short)f2b(v0.z); va[3] = (short)f2b(v0.w);
    va[4] = (short)f2b(v1.x); va[5] = (short)f2b(v1.y);
    va[6] = (short)f2b(v1.z); va[7] = (short)f2b(v1.w);
    int byteoff = (l15 * 3200 + m0 * 2) ^ ((l15 & 7) << 4);
    short8 pb = *(const short8*)(s16 + (byteoff >> 1));
    acc = __builtin_amdgcn_mfma_f32_16x16x32_bf16(va, pb, acc, 0, 0, 0);
  }
  #pragma unroll
  for (int r = 0; r < 4; ++r) red[w][(lg * 4 + r) * 16 + l15] = acc[r];
  __syncthreads();

  // final cross-wave reduction + normalize + write
  {
    int tl = t >> 8, i = (t >> 4) & 15, j = t & 15;
    int p = i * 16 + j;
    float v = red[tl][p] + red[tl + 2][p] + red[tl + 4][p] + red[tl + 6][p];
    ybuf[((size_t)(b * DIM + h * HEAD_DIM + tl * 16 + i)) * NPOS + n0 + j] = v * invs[j];
  }
}

// ---------------- kernel 4: depthwise 3x3 pe conv on v, add in place ----------------
__global__ __launch_bounds__(256) void pe_kernel(
    const float* __restrict__ vbuf, const float* __restrict__ wpe,
    const float* __restrict__ bpe, float* __restrict__ ybuf) {
  int c = blockIdx.x, b = blockIdx.y;
  const float* vp = vbuf + (size_t)(b * DIM + c) * NPOS;
  float* yp = ybuf + (size_t)(b * DIM + c) * NPOS;
  const float* w9 = wpe + c * 9;
  float w[9];
  #pragma unroll
  for (int i = 0; i < 9; ++i) w[i] = w9[i];
  float bias = bpe[c];
  for (int p = threadIdx.x; p < NPOS; p += 256) {
    int py = p / 40, px = p - py * 40;
    float acc = bias;
    #pragma unroll
    for (int dy = -1; dy <= 1; ++dy)
      #pragma unroll
      for (int dx = -1; dx <= 1; ++dx) {
        int iy = py + dy, ix = px + dx;
        if (iy >= 0 && iy < 40 && ix >= 0 && ix < 40)
          acc = fmaf(vp[iy * 40 + ix], w[(dy + 1) * 3 + (dx + 1)], acc);
      }
    yp[p] += acc;
  }
}

// ---------------- kernel 5: proj 1x1 conv -> fp32 out ----------------
__global__ __launch_bounds__(256) void proj_kernel(
    const float* __restrict__ y, const float* __restrict__ wp,
    const float* __restrict__ bp, float* __restrict__ out) {
  __shared__ float xs[64][65];
  __shared__ float wsh[64][65];
  int t = threadIdx.x;
  int n0 = blockIdx.x * 64;
  int co0 = blockIdx.y * 64;
  int b = blockIdx.z;
  int ct4 = (t >> 4) * 4, nt4 = (t & 15) * 4;
  float acc[4][4] = {};
  for (int cc = 0; cc < 4; ++cc) {
    __syncthreads();
    for (int r = 0; r < 16; ++r) {
      int idx = r * 256 + t;
      int row = idx >> 6, col = idx & 63;
      xs[row][col] = y[((size_t)(b * DIM + cc * 64 + row)) * NPOS + n0 + col];
      wsh[row][col] = wp[(size_t)(co0 + row) * DIM + cc * 64 + col];
    }
    __syncthreads();
    for (int ci = 0; ci < 64; ++ci) {
      float xv[4];
      #pragma unroll
      for (int j = 0; j < 4; ++j) xv[j] = xs[ci][nt4 + j];
      #pragma unroll
      for (int i = 0; i < 4; ++i) {
        float wv = wsh[ct4 + i][ci];
        #pragma unroll
        for (int j = 0; j < 4; ++j) acc[i][j] = fmaf(wv, xv[j], acc[i][j]);
      }
    }
  }
  for (int i = 0; i < 4; ++i) {
    int co = co0 + ct4 + i;
    float bias = bp[co];
    for (int j = 0; j < 4; ++j) {
      int n = n0 + nt4 + j;
      out[(size_t)(b * DIM + co) * NPOS + n] = acc[i][j] + bias;
    }
  }
}

extern "C" void kernel_launch(void* const* d_in, const int* in_sizes, int n_in,
                              void* d_out, int out_size, void* d_ws, size_t ws_size,
                              hipStream_t stream) {
  (void)in_sizes; (void)n_in; (void)out_size; (void)ws_size;
  const float* x = (const float*)d_in[0];
  const float* w_qkv = (const float*)d_in[1];
  const float* b_qkv = (const float*)d_in[2];
  const float* w_proj = (const float*)d_in[3];
  const float* b_proj = (const float*)d_in[4];
  const float* w_pe = (const float*)d_in[5];
  const float* b_pe = (const float*)d_in[6];
  const float* temperature = (const float*)d_in[7];
  const float* supp = (const float*)d_in[8];

  float* wsf = (float*)d_ws;
  float* qbuf = wsf;                                   // 409600 f
  float* kbuf = qbuf + 2 * HEADS * KEY_DIM * NPOS;     // 409600 f
  float* vbuf = kbuf + 2 * HEADS * KEY_DIM * NPOS;     // 819200 f
  float* ybuf = vbuf + 2 * DIM * NPOS;                 // 819200 f
  unsigned short* qT16 = (unsigned short*)(ybuf + 2 * DIM * NPOS);  // 409600 bf16
  unsigned short* kT16 = qT16 + 2 * HEADS * KEY_DIM * NPOS;         // 409600 bf16
  float* out = (float*)d_out;

  qkv_kernel<<<dim3(25, 8, 2), 256, 0, stream>>>(x, w_qkv, b_qkv, qbuf, kbuf, vbuf);
  norm_kernel<<<512, 256, 0, stream>>>(qbuf, qT16, kT16);
  attn_kernel<<<dim3(NPOS / QBLK, HEADS, 2), 512, 0, stream>>>(qT16, kT16, vbuf, temperature, supp, ybuf);
  pe_kernel<<<dim3(DIM, 2), 256, 0, stream>>>(vbuf, w_pe, b_pe, ybuf);
  proj_kernel<<<dim3(25, 4, 2), 256, 0, stream>>>(ybuf, w_proj, b_proj, out);
}

// Round 6
// 111.063 us; speedup vs baseline: 5.0012x; 1.8160x over previous
//
#include <hip/hip_runtime.h>
#include <hip/hip_bf16.h>

#define NPOS 1600
#define HEADS 8
#define KEY_DIM 16
#define HEAD_DIM 32
#define DIM 256
#define QKV_DIM 512
#define RSEL 320   // ascending 0-based order-stat index (num_keep = 1280)
#define QBLK 16
#define NBINS 256

typedef __attribute__((ext_vector_type(8))) short short8;
typedef __attribute__((ext_vector_type(4))) float f32x4;

__device__ __forceinline__ unsigned short f2b(float f) {
  unsigned u = __float_as_uint(f);
  unsigned r = u + 0x7FFFu + ((u >> 16) & 1u);
  return (unsigned short)(r >> 16);
}
__device__ __forceinline__ float b2f(unsigned short h) {
  return __uint_as_float(((unsigned)h) << 16);
}

// ---------------- kernel A: transpose x -> xT bf16 [b][n][c] ----------------
__global__ __launch_bounds__(256) void xpose_kernel(
    const float* __restrict__ x, unsigned short* __restrict__ xT16) {
  __shared__ float tile[64][65];
  int t = threadIdx.x;
  int n0 = blockIdx.x * 64, c0 = blockIdx.y * 64, b = blockIdx.z;
  for (int r = 0; r < 16; ++r) {
    int idx = r * 256 + t;
    int row = idx >> 6, col = idx & 63;
    tile[row][col] = x[((size_t)(b * DIM + c0 + row)) * NPOS + n0 + col];
  }
  __syncthreads();
  int nl = t >> 2, cc = (t & 3) * 16;
  short8 o0, o1;
  #pragma unroll
  for (int i = 0; i < 8; ++i) o0[i] = (short)f2b(tile[cc + i][nl]);
  #pragma unroll
  for (int i = 0; i < 8; ++i) o1[i] = (short)f2b(tile[cc + 8 + i][nl]);
  size_t base = ((size_t)(b * NPOS + n0 + nl)) * DIM + c0 + cc;
  *(short8*)(xT16 + base) = o0;
  *(short8*)(xT16 + base + 8) = o1;
}

// ---------------- kernel B: convert weights to bf16 ----------------
__global__ __launch_bounds__(256) void convw_kernel(
    const float* __restrict__ wq, const float* __restrict__ wp,
    unsigned short* __restrict__ wqb, unsigned short* __restrict__ wpb) {
  int idx = (blockIdx.x * 256 + threadIdx.x) * 8;
  #pragma unroll
  for (int i = 0; i < 8; ++i) {
    int e = idx + i;
    if (e < QKV_DIM * DIM) wqb[e] = f2b(wq[e]);
    else wpb[e - QKV_DIM * DIM] = f2b(wp[e - QKV_DIM * DIM]);
  }
}

// ---------------- kernel 1: qkv via MFMA ----------------
// out tile 64co x 64n per block, 4 waves (wave w -> co chunk w*16).
__global__ __launch_bounds__(256) void qkv_mfma(
    const unsigned short* __restrict__ xT16, const unsigned short* __restrict__ wqb,
    const float* __restrict__ bq, float* __restrict__ qbuf,
    float* __restrict__ kbuf, unsigned short* __restrict__ vb16) {
  int t = threadIdx.x, lane = t & 63, w = t >> 6;
  int l15 = lane & 15, lg = lane >> 4;
  int n0 = blockIdx.x * 64, co0 = blockIdx.y * 64, b = blockIdx.z;
  int cow = co0 + w * 16;
  short8 af[8];
  #pragma unroll
  for (int ks = 0; ks < 8; ++ks)
    af[ks] = *(const short8*)(wqb + (size_t)(cow + l15) * DIM + ks * 32 + lg * 8);
  f32x4 acc[4];
  #pragma unroll
  for (int sub = 0; sub < 4; ++sub) {
    int n = n0 + sub * 16 + l15;
    const unsigned short* xb = xT16 + (size_t)(b * NPOS + n) * DIM + lg * 8;
    f32x4 a = {0.f, 0.f, 0.f, 0.f};
    #pragma unroll
    for (int ks = 0; ks < 8; ++ks)
      a = __builtin_amdgcn_mfma_f32_16x16x32_bf16(af[ks], *(const short8*)(xb + ks * 32), a, 0, 0, 0);
    acc[sub] = a;
  }
  #pragma unroll
  for (int sub = 0; sub < 4; ++sub) {
    #pragma unroll
    for (int r = 0; r < 4; ++r) {
      int co = cow + lg * 4 + r;
      int n = n0 + sub * 16 + l15;
      float val = acc[sub][r] + bq[co];
      int hh = co >> 6, rr = co & 63;
      if (rr < KEY_DIM)
        qbuf[((b * HEADS + hh) * KEY_DIM + rr) * NPOS + n] = val;
      else if (rr < 2 * KEY_DIM)
        kbuf[((b * HEADS + hh) * KEY_DIM + (rr - KEY_DIM)) * NPOS + n] = val;
      else
        vb16[((size_t)(b * DIM + hh * HEAD_DIM + (rr - 2 * KEY_DIM))) * NPOS + n] = f2b(val);
    }
  }
}

// ---------------- kernel 2: L2-normalize q,k + emit bf16 transposed [bh][n][kk] ----------------
__global__ __launch_bounds__(256) void norm_kernel(
    const float* __restrict__ qbuf, const float* __restrict__ kbuf,
    unsigned short* __restrict__ qT16, unsigned short* __restrict__ kT16) {
  __shared__ float invn[16];
  __shared__ float tile[16][260];
  int bh = blockIdx.x;
  const float* src = blockIdx.y ? kbuf : qbuf;
  unsigned short* dst = blockIdx.y ? kT16 : qT16;
  const float* rows = src + (size_t)bh * 16 * NPOS;
  int t = threadIdx.x;
  int r = t >> 4, s = t & 15;
  float ss = 0.0f;
  for (int j = 0; j < 100; ++j) {
    float v = rows[r * NPOS + s + 16 * j];
    ss += v * v;
  }
  #pragma unroll
  for (int o = 8; o; o >>= 1) ss += __shfl_xor(ss, o, 64);
  if (s == 0) invn[r] = 1.0f / fmaxf(sqrtf(ss), 1e-12f);
  __syncthreads();
  float iv[16];
  #pragma unroll
  for (int kk = 0; kk < 16; ++kk) iv[kk] = invn[kk];
  for (int ch = 0; ch < 7; ++ch) {
    int m = ch * 256 + t;
    __syncthreads();
    if (m < NPOS)
      for (int kk = 0; kk < 16; ++kk) tile[kk][t] = rows[kk * NPOS + m];
    __syncthreads();
    if (m < NPOS) {
      short8 o0, o1;
      #pragma unroll
      for (int i = 0; i < 8; ++i) o0[i] = (short)f2b(tile[i][t] * iv[i]);
      #pragma unroll
      for (int i = 0; i < 8; ++i) o1[i] = (short)f2b(tile[8 + i][t] * iv[8 + i]);
      size_t base = ((size_t)bh * NPOS + m) * KEY_DIM;
      *(short8*)(dst + base) = o0;
      *(short8*)(dst + base + 8) = o1;
    }
  }
}

// ---------------- kernel 3: fused attention, MFMA + fused pe-conv epilogue ----------------
__global__ __launch_bounds__(512) void attn_kernel(
    const unsigned short* __restrict__ qT16, const unsigned short* __restrict__ kT16,
    const unsigned short* __restrict__ vb16, const float* __restrict__ temp,
    const float* __restrict__ supp, const float* __restrict__ wpe,
    const float* __restrict__ bpe, unsigned short* __restrict__ ybT) {
  __shared__ __align__(128) unsigned short s16[QBLK * NPOS];  // 51200 B
  __shared__ unsigned hist[8][NBINS];
  __shared__ float red[8][256];
  __shared__ float invs[QBLK];
  int t = threadIdx.x, lane = t & 63, w = t >> 6;
  int l15 = lane & 15, lg = lane >> 4;
  int n0 = blockIdx.x * QBLK;
  int h = blockIdx.y, b = blockIdx.z;
  int bh = b * HEADS + h;
  float tscale = temp[h];
  float sgm = 1.0f / (1.0f + __expf(-supp[0]));

  short8 qa = {0, 0, 0, 0, 0, 0, 0, 0};
  if (lane < 32)
    qa = *(const short8*)(qT16 + ((size_t)bh * NPOS + n0 + l15) * KEY_DIM + lg * 8);

  for (int mt = w; mt < NPOS / 16; mt += 8) {
    int m0 = mt * 16;
    short8 kb = {0, 0, 0, 0, 0, 0, 0, 0};
    if (lane < 32)
      kb = *(const short8*)(kT16 + ((size_t)bh * NPOS + m0 + l15) * KEY_DIM + lg * 8);
    f32x4 acc = {0.f, 0.f, 0.f, 0.f};
    acc = __builtin_amdgcn_mfma_f32_16x16x32_bf16(qa, kb, acc, 0, 0, 0);
    #pragma unroll
    for (int r = 0; r < 4; ++r) {
      int row = lg * 4 + r;
      int byteoff = (row * 3200 + (m0 + l15) * 2) ^ ((row & 7) << 4);
      s16[byteoff >> 1] = f2b(acc[r] * tscale);
    }
  }
  __syncthreads();

  for (int rl = 0; rl < 2; ++rl) {
    int rr = w * 2 + rl;
    int rbase = rr * 3200, xr = (rr & 7) << 4;
    float sv[25];
    float mn = 3.4e38f, mx = -3.4e38f;
    #pragma unroll
    for (int k = 0; k < 25; ++k) {
      int byteoff = rbase + (((lane + 64 * k) * 2) ^ xr);
      float v = b2f(s16[byteoff >> 1]);
      sv[k] = v; mn = fminf(mn, v); mx = fmaxf(mx, v);
    }
    #pragma unroll
    for (int k4 = 0; k4 < 4; ++k4) hist[w][lane * 4 + k4] = 0;
    #pragma unroll
    for (int o = 32; o; o >>= 1) {
      mn = fminf(mn, __shfl_xor(mn, o, 64));
      mx = fmaxf(mx, __shfl_xor(mx, o, 64));
    }
    float range = fmaxf(mx - mn, 1e-30f) * 1.000001f;
    float invw = (float)NBINS / range;
    #pragma unroll
    for (int k = 0; k < 25; ++k) {
      int idx = (int)((sv[k] - mn) * invw);
      idx = idx < 0 ? 0 : (idx > NBINS - 1 ? NBINS - 1 : idx);
      atomicAdd(&hist[w][idx], 1u);
    }
    int h0 = (int)hist[w][4 * lane], h1 = (int)hist[w][4 * lane + 1];
    int h2 = (int)hist[w][4 * lane + 2], h3 = (int)hist[w][4 * lane + 3];
    int lsum = h0 + h1 + h2 + h3;
    int incl = lsum;
    #pragma unroll
    for (int o = 1; o < 64; o <<= 1) {
      int xx = __shfl_up(incl, o, 64);
      if (lane >= o) incl += xx;
    }
    int c = incl - lsum;
    int cand = 1 << 30;
    if (c <= RSEL && c + h0 > RSEL) cand = 4 * lane;
    c += h0; if (c <= RSEL && c + h1 > RSEL) cand = 4 * lane + 1;
    c += h1; if (c <= RSEL && c + h2 > RSEL) cand = 4 * lane + 2;
    c += h2; if (c <= RSEL && c + h3 > RSEL) cand = 4 * lane + 3;
    #pragma unroll
    for (int o = 32; o; o >>= 1) cand = min(cand, __shfl_xor(cand, o, 64));
    float thr = mn + (float)cand * (range / (float)NBINS);

    float lmax = -3.4e38f;
    #pragma unroll
    for (int k = 0; k < 25; ++k) {
      float p = sv[k] * (sv[k] >= thr ? 1.0f : sgm);
      sv[k] = p;
      lmax = fmaxf(lmax, p);
    }
    #pragma unroll
    for (int o = 32; o; o >>= 1) lmax = fmaxf(lmax, __shfl_xor(lmax, o, 64));
    float lsumf = 0.0f;
    #pragma unroll
    for (int k = 0; k < 25; ++k) {
      float e = __expf(sv[k] - lmax);
      lsumf += e;
      int byteoff = rbase + (((lane + 64 * k) * 2) ^ xr);
      s16[byteoff >> 1] = f2b(e);
    }
    #pragma unroll
    for (int o = 32; o; o >>= 1) lsumf += __shfl_xor(lsumf, o, 64);
    if (lane == 0) invs[rr] = 1.0f / lsumf;
  }
  __syncthreads();

  // PV
  int tile = w & 1, d0 = tile * 16;
  const unsigned short* vrow = vb16 + ((size_t)(b * DIM + h * HEAD_DIM + d0 + l15)) * NPOS;
  f32x4 acc = {0.f, 0.f, 0.f, 0.f};
  for (int c = (w >> 1); c < NPOS / 32; c += 4) {
    int m0 = c * 32 + lg * 8;
    short8 va = *(const short8*)(vrow + m0);
    int byteoff = (l15 * 3200 + m0 * 2) ^ ((l15 & 7) << 4);
    short8 pb = *(const short8*)(s16 + (byteoff >> 1));
    acc = __builtin_amdgcn_mfma_f32_16x16x32_bf16(va, pb, acc, 0, 0, 0);
  }
  #pragma unroll
  for (int r = 0; r < 4; ++r) red[w][(lg * 4 + r) * 16 + l15] = acc[r];
  __syncthreads();

  // epilogue: cross-wave reduce + normalize + fused pe conv + bf16 transposed store
  {
    int tl = t >> 8, i = (t >> 4) & 15, j = t & 15;
    int p = i * 16 + j;
    float v = red[tl][p] + red[tl + 2][p] + red[tl + 4][p] + red[tl + 6][p];
    int c = h * HEAD_DIM + tl * 16 + i;
    int n = n0 + j;
    float o = v * invs[j];
    // depthwise 3x3 pe conv on v at (c, n)
    int py = n / 40, px = n - py * 40;
    const unsigned short* vp = vb16 + (size_t)(b * DIM + c) * NPOS;
    const float* w9 = wpe + c * 9;
    float acc2 = bpe[c];
    #pragma unroll
    for (int dy = -1; dy <= 1; ++dy) {
      int iy = py + dy;
      if (iy < 0 || iy > 39) continue;
      #pragma unroll
      for (int dx = -1; dx <= 1; ++dx) {
        int ix = px + dx;
        if (ix < 0 || ix > 39) continue;
        acc2 = fmaf(b2f(vp[iy * 40 + ix]), w9[(dy + 1) * 3 + (dx + 1)], acc2);
      }
    }
    o += acc2;
    ybT[((size_t)(b * NPOS + n)) * DIM + c] = f2b(o);
  }
}

// ---------------- kernel 5: proj via MFMA -> fp32 out ----------------
__global__ __launch_bounds__(256) void proj_mfma(
    const unsigned short* __restrict__ ybT, const unsigned short* __restrict__ wpb,
    const float* __restrict__ bp, float* __restrict__ out) {
  int t = threadIdx.x, lane = t & 63, w = t >> 6;
  int l15 = lane & 15, lg = lane >> 4;
  int n0 = blockIdx.x * 64, co0 = blockIdx.y * 64, b = blockIdx.z;
  int cow = co0 + w * 16;
  short8 af[8];
  #pragma unroll
  for (int ks = 0; ks < 8; ++ks)
    af[ks] = *(const short8*)(wpb + (size_t)(cow + l15) * DIM + ks * 32 + lg * 8);
  f32x4 acc[4];
  #pragma unroll
  for (int sub = 0; sub < 4; ++sub) {
    int n = n0 + sub * 16 + l15;
    const unsigned short* yb = ybT + (size_t)(b * NPOS + n) * DIM + lg * 8;
    f32x4 a = {0.f, 0.f, 0.f, 0.f};
    #pragma unroll
    for (int ks = 0; ks < 8; ++ks)
      a = __builtin_amdgcn_mfma_f32_16x16x32_bf16(af[ks], *(const short8*)(yb + ks * 32), a, 0, 0, 0);
    acc[sub] = a;
  }
  #pragma unroll
  for (int sub = 0; sub < 4; ++sub) {
    #pragma unroll
    for (int r = 0; r < 4; ++r) {
      int co = cow + lg * 4 + r;
      int n = n0 + sub * 16 + l15;
      out[((size_t)(b * DIM + co)) * NPOS + n] = acc[sub][r] + bp[co];
    }
  }
}

extern "C" void kernel_launch(void* const* d_in, const int* in_sizes, int n_in,
                              void* d_out, int out_size, void* d_ws, size_t ws_size,
                              hipStream_t stream) {
  (void)in_sizes; (void)n_in; (void)out_size; (void)ws_size;
  const float* x = (const float*)d_in[0];
  const float* w_qkv = (const float*)d_in[1];
  const float* b_qkv = (const float*)d_in[2];
  const float* w_proj = (const float*)d_in[3];
  const float* b_proj = (const float*)d_in[4];
  const float* w_pe = (const float*)d_in[5];
  const float* b_pe = (const float*)d_in[6];
  const float* temperature = (const float*)d_in[7];
  const float* supp = (const float*)d_in[8];

  float* wsf = (float*)d_ws;
  float* qbuf = wsf;                                    // 409600 f
  float* kbuf = qbuf + 409600;                          // 409600 f
  unsigned short* vb16 = (unsigned short*)(kbuf + 409600);  // 819200 bf16
  unsigned short* qT16 = vb16 + 819200;                 // 409600
  unsigned short* kT16 = qT16 + 409600;                 // 409600
  unsigned short* xT16 = kT16 + 409600;                 // 819200
  unsigned short* ybT  = xT16 + 819200;                 // 819200
  unsigned short* wqb  = ybT + 819200;                  // 131072
  unsigned short* wpb  = wqb + 131072;                  // 65536
  float* out = (float*)d_out;

  xpose_kernel<<<dim3(25, 4, 2), 256, 0, stream>>>(x, xT16);
  convw_kernel<<<dim3(96, 1, 1), 256, 0, stream>>>(w_qkv, w_proj, wqb, wpb);
  qkv_mfma<<<dim3(25, 8, 2), 256, 0, stream>>>(xT16, wqb, b_qkv, qbuf, kbuf, vb16);
  norm_kernel<<<dim3(16, 2), 256, 0, stream>>>(qbuf, kbuf, qT16, kT16);
  attn_kernel<<<dim3(NPOS / QBLK, HEADS, 2), 512, 0, stream>>>(qT16, kT16, vb16, temperature, supp, w_pe, b_pe, ybT);
  proj_mfma<<<dim3(25, 4, 2), 256, 0, stream>>>(ybT, wpb, b_proj, out);
}